// Round 1
// 898.654 us; speedup vs baseline: 1.0540x; 1.0540x over previous
//
#include <hip/hip_runtime.h>

// Problem constants:
//   x:      (B=4, J=2048, M=4096) fp32  -> rows R = B*J = 8192, row-major M
//   lora_A: (N=4, D=16, M=4096)   fp32  -> ND = 64 rows, row-major M
//   lora_B: (N=4, K=4096, D=16)   fp32
//   out:    (N, B, J, K) fp32 = (n*R + row)*K + k   (512 MiB, write-bound)
//   t:      t[n][row][d] = sum_m x[row][m] * A[nd][m], nd = n*16+d  (2 MiB)

#define MDIM 4096
#define KDIM 4096
#define RDIM 8192
#define NADP 4
#define NPARTS 8                      // m-split factor (was 2)
#define MPART (MDIM / NPARTS)         // 512 floats per split
#define TPART_FLOATS (NADP * RDIM * 16)   // floats per m-part partial (2 MiB)
// workspace: NPARTS * 2 MiB = 16 MiB

// ---------------- Stage 1: tpart[mh][n][row][d] = x . A^T (m-slice) --------
// Grid: (256 row-chunks of 32 rows, 8 m-parts) = 2048 blocks (8/CU nominal)
// vs previous 512 (2/CU): 4x the waves + unroll 4 (~36 loads in flight/wave)
// to hide HBM latency on the wave-uniform x stream. Lane = nd; x rides
// broadcast/scalar path, A rides VMEM/L1.
__global__ __launch_bounds__(256) void lora_stage1(
    const float* __restrict__ x, const float* __restrict__ A,
    float* __restrict__ tpart) {
  const int tid = threadIdx.x;
  const int nd  = tid & 63;
  const int wv  = __builtin_amdgcn_readfirstlane(tid >> 6);  // wave id, uniform
  const int rb  = blockIdx.x;   // 0..255
  const int mh  = blockIdx.y;   // 0..7
  const int row0 = rb * 32 + wv * 8;
  const int m0   = mh * MPART;

  const float* Arow = A + (size_t)nd * MDIM + m0;
  const float* xr0  = x + (size_t)row0 * MDIM + m0;

  float acc[8];
#pragma unroll
  for (int r = 0; r < 8; ++r) acc[r] = 0.f;

#pragma unroll 4
  for (int m = 0; m < MPART; m += 4) {
    const float4 a4 = *(const float4*)(Arow + m);
#pragma unroll
    for (int r = 0; r < 8; ++r) {
      const float4 xv = *(const float4*)(xr0 + (size_t)r * MDIM + m);  // uniform
      acc[r] = fmaf(xv.w, a4.w,
               fmaf(xv.z, a4.z,
               fmaf(xv.y, a4.y,
               fmaf(xv.x, a4.x, acc[r]))));
    }
  }

  const int n = nd >> 4, d = nd & 15;
  float* tp = tpart + (size_t)mh * TPART_FLOATS;
#pragma unroll
  for (int r = 0; r < 8; ++r) {
    tp[((size_t)n * RDIM + (row0 + r)) * 16 + d] = acc[r];
  }
}

// ---------------- Stage 2: out[n][row][k] = t[n][row][:] . B[n][k][:] ------
// Grid: (4 k-tiles of 1024, N=4, 64 row-chunks of 128) = 1024 blocks.
// Changes vs previous:
//  * 128 rows/block (was 32): the per-thread B fragment (lane stride 256 B ->
//    ~64 TA splits per load instr) is fetched 4x less often.
//  * The NPARTS partial-t reduction is done ONCE per block into an 8 KiB LDS
//    tile (coalesced float4 global reads), so the row loop has zero partial
//    adds: 4 broadcast ds_read_b128 + 64 FMA + one 1 KiB coalesced store.
__global__ __launch_bounds__(256) void lora_stage2(
    const float* __restrict__ tpart, const float* __restrict__ Bm,
    float* __restrict__ out) {
  __shared__ float4 tlds[512];        // t[128 rows][16 d] = 8 KiB
  const int tid = threadIdx.x;
  const int kb  = blockIdx.x;   // 0..3
  const int n   = blockIdx.y;   // 0..3
  const int rc  = blockIdx.z;   // 0..63
  const int kk  = kb * 1024 + tid * 4;
  const int row0 = rc * 128;

  // ---- reduce the 8 m-part partials for this block's 128 t-rows into LDS
  // slot s = (row-row0)*4 + q (float4 granules); lanes contiguous per part.
  const float4* tp4 = (const float4*)tpart + ((size_t)n * RDIM + row0) * 4;
  const size_t pstr4 = TPART_FLOATS / 4;
#pragma unroll
  for (int s0 = 0; s0 < 2; ++s0) {
    const int s = tid + s0 * 256;
    float4 sum = tp4[s];
#pragma unroll
    for (int p = 1; p < NPARTS; ++p) {
      const float4 v = tp4[(size_t)p * pstr4 + s];
      sum.x += v.x; sum.y += v.y; sum.z += v.z; sum.w += v.w;
    }
    tlds[s] = sum;
  }

  // ---- B fragment: rows kk..kk+3, 16 d each (256 B/thread), reused 128 rows
  const float* Bn = Bm + ((size_t)n * KDIM + kk) * 16;
  float4 b[4][4];
#pragma unroll
  for (int i = 0; i < 4; ++i) {
#pragma unroll
    for (int q = 0; q < 4; ++q) {
      b[i][q] = *(const float4*)(Bn + i * 16 + q * 4);
    }
  }

  __syncthreads();

  float* orow = out + ((size_t)n * RDIM + row0) * KDIM + kk;
#pragma unroll 2
  for (int r = 0; r < 128; ++r) {
    float4 tv[4];
#pragma unroll
    for (int q = 0; q < 4; ++q) {
      tv[q] = tlds[r * 4 + q];        // uniform broadcast, conflict-free
    }
    float4 o;
    float* op = (float*)&o;
#pragma unroll
    for (int i = 0; i < 4; ++i) {
      float s = 0.f;
#pragma unroll
      for (int q = 0; q < 4; ++q) {
        s = fmaf(tv[q].x, b[i][q].x, s);
        s = fmaf(tv[q].y, b[i][q].y, s);
        s = fmaf(tv[q].z, b[i][q].z, s);
        s = fmaf(tv[q].w, b[i][q].w, s);
      }
      op[i] = s;
    }
    *(float4*)(orow + (size_t)r * KDIM) = o;
  }
}

extern "C" void kernel_launch(void* const* d_in, const int* in_sizes, int n_in,
                              void* d_out, int out_size, void* d_ws, size_t ws_size,
                              hipStream_t stream) {
  const float* x  = (const float*)d_in[0];   // 4*2048*4096
  const float* A  = (const float*)d_in[1];   // 4*16*4096
  const float* Bm = (const float*)d_in[2];   // 4*4096*16
  float* out   = (float*)d_out;              // 4*4*2048*4096
  float* tpart = (float*)d_ws;               // 8 * 2 MiB partials = 16 MiB

  dim3 g1(256, NPARTS, 1);
  lora_stage1<<<g1, 256, 0, stream>>>(x, A, tpart);

  dim3 g2(4, 4, 64);
  lora_stage2<<<g2, 256, 0, stream>>>(tpart, Bm, out);
}